// Round 1
// baseline (589.512 us; speedup 1.0000x reference)
//
#include <hip/hip_runtime.h>
#include <math.h>

#define DEV static __device__ __forceinline__

DEV double shfl8d(double v, int k){ return __shfl(v, k, 8); }
DEV double xor8d(double v, int msk){ return __shfl_xor(v, msk, 8); }
DEV float  shfl8f(float v, int k){ return __shfl(v, k, 8); }
DEV float  xor8f(float v, int msk){ return __shfl_xor(v, msk, 8); }

DEV double sel8d(const double* a, int i){
  double v = a[0];
#pragma unroll
  for (int j=1;j<8;j++) v = (i==j) ? a[j] : v;
  return v;
}
DEV float sel8f(const float* a, int i){
  float v = a[0];
#pragma unroll
  for (int j=1;j<8;j++) v = (i==j) ? a[j] : v;
  return v;
}
DEV int sel8i(const int* a, int i){
  int v = a[0];
#pragma unroll
  for (int j=1;j<8;j++) v = (i==j) ? a[j] : v;
  return v;
}

#define CE(i,j) { double lo_ = fmin(d[i], d[j]); double hi_ = fmax(d[i], d[j]); d[i]=lo_; d[j]=hi_; }

// ---------------------------------------------------------------------------
// K1: scale, Ad, LeVerrier coefficients c[0..8], char_coeffs (f32), zi seeds.
// 8 threads per matrix (one row each); shuffle-based 8x8 f64 matmuls.
// ---------------------------------------------------------------------------
__global__ __launch_bounds__(256) void k1_charpoly(
    const float* __restrict__ A, double* __restrict__ ws_c, double* __restrict__ ws_zi,
    double* __restrict__ ws_scale, float* __restrict__ out_char, int B)
{
#pragma clang fp contract(off)
  int t = blockIdx.x*256 + threadIdx.x;
  int m = t >> 3, r = t & 7;
  if (m >= B) return;
  const float* Am = A + (size_t)m*64 + (size_t)r*8;
  float a[8];
#pragma unroll
  for (int j=0;j<8;j++) a[j] = Am[j];
  // ||A||_F^2 in f32. Per-lane sequential row dot == numpy stride-8 pairwise
  // accumulator (bitwise, since A is exactly symmetric); xor-tree == numpy's
  // ((r0+r1)+(r2+r3))+((r4+r5)+(r6+r7)) combine (add commutativity).
  float ss = a[0]*a[0];
#pragma unroll
  for (int j=1;j<8;j++) ss = ss + a[j]*a[j];
  ss = ss + xor8f(ss,1);
  ss = ss + xor8f(ss,2);
  ss = ss + xor8f(ss,4);
  float nrm = sqrtf(ss);
  // f32 norm / np.float64 sqrt(8) promotes to f64 (JAX x64 / NEP50): scale is f64.
  double scale = (double)nrm / 2.8284271247461903;
  scale = fmax(scale, 1e-12);
  double Ad[8];
#pragma unroll
  for (int j=0;j<8;j++) Ad[j] = (double)a[j] / scale;   // As == Ad (f64)

  double c[9];
#pragma unroll
  for (int j=0;j<9;j++) c[j] = 0.0;
  c[8] = 1.0;
  double Mcur[8];
#pragma unroll
  for (int j=0;j<8;j++) Mcur[j] = (j==r) ? 1.0 : 0.0;   // M1 = I
#pragma unroll
  for (int k=1;k<=8;k++){
    if (k > 1){
      double ck = c[9-k];
      double Mn[8];
#pragma unroll
      for (int kk=0;kk<8;kk++){
        double br[8];
#pragma unroll
        for (int j=0;j<8;j++) br[j] = shfl8d(Mcur[j], kk);  // row kk of M_{k-1}
        if (kk == 0){
#pragma unroll
          for (int j=0;j<8;j++) Mn[j] = Ad[0]*br[j];
        } else {
#pragma unroll
          for (int j=0;j<8;j++) Mn[j] = fma(Ad[kk], br[j], Mn[j]);
        }
      }
#pragma unroll
      for (int j=0;j<8;j++) Mcur[j] = Mn[j] + ((j==r) ? ck : 0.0);
    }
    // trace term: (Ad*Mk).sum((-2,-1)), numpy pairwise order
    double s = Ad[0]*Mcur[0];
#pragma unroll
    for (int j=1;j<8;j++) s = s + Ad[j]*Mcur[j];
    s = s + xor8d(s,1);
    s = s + xor8d(s,2);
    s = s + xor8d(s,4);
    c[8-k] = (-s) / (double)k;
  }
  double* cw = ws_c + (size_t)m*9;
  cw[r] = c[r];
  if (r == 0) cw[8] = c[8];
  out_char[(size_t)m*8 + r] = (float)c[r];

  // zi = sort(diag(Ad)) + np.linspace(-1e-4, 1e-4, 8)
  double diag = sel8d(Ad, r);
  double d[8];
#pragma unroll
  for (int k=0;k<8;k++) d[k] = shfl8d(diag, k);
  CE(0,1) CE(2,3) CE(4,5) CE(6,7)
  CE(0,2) CE(1,3) CE(4,6) CE(5,7)
  CE(1,2) CE(5,6)
  CE(0,4) CE(1,5) CE(2,6) CE(3,7)
  CE(2,4) CE(3,5)
  CE(1,2) CE(3,4) CE(5,6)
  double step = 2e-4/7.0;                 // numpy: y = arange*step, y += start
  double lin = (double)r * step + (-1e-4);
  if (r == 7) lin = 1e-4;                 // numpy endpoint: y[-1] = stop
  ws_zi[(size_t)m*8 + r] = sel8d(d, r) + lin;
  if (r == 0) ws_scale[m] = scale;
}

// ---------------------------------------------------------------------------
// K2: Laguerre rings + deflation + Newton polish. 1 thread per matrix.
// Exact op-order replication of the reference (fp contract off).
// ---------------------------------------------------------------------------
__global__ __launch_bounds__(256) void k2_roots(
    const double* __restrict__ ws_c, const double* __restrict__ ws_zi,
    double* __restrict__ ws_lam, float* __restrict__ ws_fr, float* __restrict__ ws_st, int B)
{
#pragma clang fp contract(off)
  int m = blockIdx.x*256 + threadIdx.x;
  if (m >= B) return;
  const double* cp = ws_c + (size_t)m*9;
  double c[9], cl[9];
#pragma unroll
  for (int j=0;j<9;j++){ c[j] = cp[j]; cl[j] = c[j]; }
  const double* zp = ws_zi + (size_t)m*8;
  double roots[8];
  float* frp = ws_fr + (size_t)m*8;
  float* stp = ws_st + (size_t)m*8;
#pragma unroll
  for (int ri=0;ri<8;ri++){
    const int deg = 8 - ri;
    double z = zp[ri];
    float fr = 0.0f, st = 5.0f;
#pragma unroll
    for (int li=0; li<5; li++){
      double pv = cl[deg], dp = 0.0, d2 = 0.0;
#pragma unroll
      for (int j=deg-1;j>=0;j--){
        d2 = d2*z + dp;
        dp = dp*z + pv;
        pv = pv*z + cl[j];
      }
      float dp_abs = (float)fabs(dp);
      fr = fr + 1.0f/(dp_abs + 1e-8f);
      float pv_abs = (float)fabs(pv);
      if ((pv_abs < 1e-6f) && (st == 5.0f)) st = (float)li;
      bool ok = fabs(pv) > 1e-30;
      double ps = ok ? pv : 1.0;
      double G  = ok ? dp/ps : 0.0;
      double t2 = ok ? (2.0*d2)/ps : 0.0;
      double GG = G*G;
      double H  = GG - t2;
      double t3 = (double)deg*H - GG;
      double t4 = ((double)deg - 1.0) * t3;
      double disc = (t4 < 0.0) ? 0.0 : t4;   // np.maximum(x,0): NaN propagates
      double sq = sqrt(disc);
      double gp = G + sq, gm = G - sq;
      double den = (fabs(gp) >= fabs(gm)) ? gp : gm;
      bool dok = fabs(den) > 1e-20;
      double dsv = dok ? den : 1.0;
      z = z - (dok ? (double)deg/dsv : 0.0);
    }
    roots[ri] = z;
    frp[ri] = fr;
    stp[ri] = st;
    // deflation (synthetic division by (x - z))
    double b = cl[deg];
    double nc[8];
#pragma unroll
    for (int j=deg-1;j>=1;j--){
      double bn = cl[j] + z*b;
      nc[j] = b;
      b = bn;
    }
    nc[0] = b;
#pragma unroll
    for (int j=0;j<deg;j++) cl[j] = nc[j];
  }
  // Newton polish (3 iters, original c, implicit leading 1)
#pragma unroll
  for (int it=0; it<3; it++){
#pragma unroll
    for (int i=0;i<8;i++){
      double rt = roots[i];
      double pv = 1.0, dp = 0.0;
#pragma unroll
      for (int j=7;j>=0;j--){
        dp = dp*rt + pv;
        pv = pv*rt + c[j];
      }
      bool ok = fabs(dp) > 1e-30;
      double dps = ok ? dp : 1.0;
      roots[i] = rt - (ok ? pv/dps : 0.0);
    }
  }
  double* lp = ws_lam + (size_t)m*8;
#pragma unroll
  for (int j=0;j<8;j++) lp[j] = roots[j];
}

// ---------------------------------------------------------------------------
// K3: resolvent eigenvectors (f64) + Newton-Schulz (f32, LDS) + sorted outputs.
// 8 threads per matrix (one row each). M2..M8 kept in registers.
// ---------------------------------------------------------------------------
__global__ __launch_bounds__(256) void k3_eig(
    const float* __restrict__ A, const double* __restrict__ ws_c,
    const double* __restrict__ ws_lam, const double* __restrict__ ws_scale,
    const float* __restrict__ ws_fr, const float* __restrict__ ws_st,
    float* __restrict__ out, int B)
{
#pragma clang fp contract(off)
  __shared__ float sV[32*72], sY[32*72], sT[32*72], sX[32*72];  // stride 9 pad
  int t = blockIdx.x*256 + threadIdx.x;
  int m = t >> 3, r = t & 7;
  bool act = (m < B);
  if (!act) m = 0;
  int ml = threadIdx.x >> 3;
  float* mV = sV + ml*72;
  float* mY = sY + ml*72;
  float* mT = sT + ml*72;
  float* mX = sX + ml*72;

  const float* Am = A + (size_t)m*64 + (size_t)r*8;
  float a[8];
#pragma unroll
  for (int j=0;j<8;j++) a[j] = Am[j];
  double scale = ws_scale[m];
  double Ad[8];
#pragma unroll
  for (int j=0;j<8;j++) Ad[j] = (double)a[j] / scale;
  double lam[8];
  const double* lp = ws_lam + (size_t)m*8;
#pragma unroll
  for (int j=0;j<8;j++) lam[j] = lp[j];
  const double* cp = ws_c + (size_t)m*9;
  double cc[8];
#pragma unroll
  for (int j=1;j<8;j++) cc[j] = cp[j];

  // Recompute M2..M8 (row r of each)
  double M[7][8];
  {
    double Mcur[8];
#pragma unroll
    for (int j=0;j<8;j++) Mcur[j] = (j==r) ? 1.0 : 0.0;
#pragma unroll
    for (int k=2;k<=8;k++){
      double ck = cc[9-k];
      double Mn[8];
#pragma unroll
      for (int kk=0;kk<8;kk++){
        double br[8];
#pragma unroll
        for (int j=0;j<8;j++) br[j] = shfl8d(Mcur[j], kk);
        if (kk==0){
#pragma unroll
          for (int j=0;j<8;j++) Mn[j] = Ad[0]*br[j];
        } else {
#pragma unroll
          for (int j=0;j<8;j++) Mn[j] = fma(Ad[kk], br[j], Mn[j]);
        }
      }
#pragma unroll
      for (int j=0;j<8;j++) Mcur[j] = Mn[j] + ((j==r) ? ck : 0.0);
#pragma unroll
      for (int j=0;j<8;j++) M[k-2][j] = Mcur[j];
    }
  }

  // Per eigenvalue: R(lam_i) Horner, column-norm argmax, normalized vector
  float Vrow[8];  // Vrow[i] = V[r][i]
#pragma unroll
  for (int i=0;i<8;i++){
    double li = lam[i];
    double R[8];
#pragma unroll
    for (int j=0;j<8;j++) R[j] = (j==r) ? 1.0 : 0.0;   // M1 = I
#pragma unroll
    for (int k=0;k<7;k++){
#pragma unroll
      for (int j=0;j<8;j++){
        double tt = R[j]*li;
        R[j] = tt + M[k][j];
      }
    }
    double sq[8];
#pragma unroll
    for (int j=0;j<8;j++) sq[j] = R[j]*R[j];
#pragma unroll
    for (int j=0;j<8;j++) sq[j] = sq[j] + xor8d(sq[j],1);
#pragma unroll
    for (int j=0;j<8;j++) sq[j] = sq[j] + xor8d(sq[j],2);
#pragma unroll
    for (int j=0;j<8;j++) sq[j] = sq[j] + xor8d(sq[j],4);
    int best = 0;
    double bv = sqrt(sq[0]);
#pragma unroll
    for (int j=1;j<8;j++){
      double cn = sqrt(sq[j]);
      if (cn > bv){ bv = cn; best = j; }   // first-max == np.argmax
    }
    double vr = sel8d(R, best);
    double vs = vr*vr;
    vs = vs + xor8d(vs,1);
    vs = vs + xor8d(vs,2);
    vs = vs + xor8d(vs,4);
    double nn = sqrt(vs);
    Vrow[i] = (float)(vr / (nn + 1e-30));
  }

  // ---- f32 Newton-Schulz phase through LDS ----
#pragma unroll
  for (int j=0;j<8;j++) mV[r*9+j] = Vrow[j];
  __syncthreads();
  float Yrow[8];
#pragma unroll
  for (int j=0;j<8;j++){
    float s = 0.0f;
#pragma unroll
    for (int k=0;k<8;k++) s = fmaf(mV[k*9+r], mV[k*9+j], s);  // (V^T V)[r][j]
    Yrow[j] = s;
  }
  float Xrow[8];
#pragma unroll
  for (int j=0;j<8;j++) Xrow[j] = (j==r) ? 1.0f : 0.0f;
#pragma unroll
  for (int j=0;j<8;j++) mY[r*9+j] = Yrow[j];
  __syncthreads();
#pragma unroll
  for (int it=0; it<2; it++){
    float Trow[8];
#pragma unroll
    for (int j=0;j<8;j++) Trow[j] = ((j==r) ? 3.0f : 0.0f) - Yrow[j];
#pragma unroll
    for (int j=0;j<8;j++) mT[r*9+j] = Trow[j];
    __syncthreads();
    float Xn[8], Yn[8];
#pragma unroll
    for (int j=0;j<8;j++){
      float s = 0.0f;
#pragma unroll
      for (int k=0;k<8;k++) s = fmaf(Xrow[k], mT[k*9+j], s);
      Xn[j] = 0.5f*s;
    }
#pragma unroll
    for (int j=0;j<8;j++){
      float s = 0.0f;
#pragma unroll
      for (int k=0;k<8;k++) s = fmaf(Trow[k], mY[k*9+j], s);
      Yn[j] = 0.5f*s;
    }
    __syncthreads();
#pragma unroll
    for (int j=0;j<8;j++){ mY[r*9+j] = Yn[j]; Yrow[j] = Yn[j]; Xrow[j] = Xn[j]; }
    __syncthreads();
  }
  // V = V X
#pragma unroll
  for (int j=0;j<8;j++) mX[r*9+j] = Xrow[j];
  __syncthreads();
  float Vn[8];
#pragma unroll
  for (int j=0;j<8;j++){
    float s = 0.0f;
#pragma unroll
    for (int k=0;k<8;k++) s = fmaf(Vrow[k], mX[k*9+j], s);
    Vn[j] = s;
  }
  __syncthreads();
#pragma unroll
  for (int j=0;j<8;j++) mV[r*9+j] = Vn[j];
  __syncthreads();
  // VtV, residual
  float Erow[8];
#pragma unroll
  for (int j=0;j<8;j++){
    float s = 0.0f;
#pragma unroll
    for (int k=0;k<8;k++) s = fmaf(mV[k*9+r], mV[k*9+j], s);
    Erow[j] = s - ((j==r) ? 1.0f : 0.0f);
  }
  float rs = Erow[0]*Erow[0];
#pragma unroll
  for (int j=1;j<8;j++) rs = rs + Erow[j]*Erow[j];
  rs = rs + xor8f(rs,1);
  rs = rs + xor8f(rs,2);
  rs = rs + xor8f(rs,4);
  float resid = sqrtf(rs);
  // AV, evals (sequential cross-lane sum, numpy non-contiguous-axis order)
  float AVrow[8];
#pragma unroll
  for (int j=0;j<8;j++){
    float s = 0.0f;
#pragma unroll
    for (int k=0;k<8;k++) s = fmaf(a[k], mV[k*9+j], s);
    AVrow[j] = s;
  }
  float q[8];
#pragma unroll
  for (int i=0;i<8;i++) q[i] = Vn[i]*AVrow[i];
  float ev[8];
#pragma unroll
  for (int i=0;i<8;i++){
    float s = shfl8f(q[i], 0);
#pragma unroll
    for (int k=1;k<8;k++) s = s + shfl8f(q[i], k);
    ev[i] = s;
  }
  // stable ascending argsort of evals (redundant per lane)
  int perm[8];
  unsigned used = 0;
#pragma unroll
  for (int p=0;p<8;p++){
    int bi = -1; float bvv = 0.0f;
#pragma unroll
    for (int i2=0;i2<8;i2++){
      bool u = (used >> i2) & 1u;
      bool take = !u && (bi < 0 || ev[i2] < bvv);
      bi = take ? i2 : bi;
      bvv = take ? ev[i2] : bvv;
    }
    perm[p] = bi;
    used |= (1u << bi);
  }
  int oi = sel8i(perm, r);       // this lane handles output column r
  float col[8];
#pragma unroll
  for (int j=0;j<8;j++) col[j] = mV[j*9 + oi];
  int mi = 0; float mv = fabsf(col[0]);
#pragma unroll
  for (int j=1;j<8;j++){
    float aj = fabsf(col[j]);
    if (aj > mv){ mv = aj; mi = j; }
  }
  float v0 = sel8f(col, mi);
  float sgn = (v0 > 0.0f) ? 1.0f : ((v0 < 0.0f) ? -1.0f : v0);  // np.sign
  if (act){
    out[(size_t)m*8 + r] = sel8f(ev, oi);                          // se
    float* svp = out + (size_t)B*8 + (size_t)m*64;                 // sv
#pragma unroll
    for (int j=0;j<8;j++) svp[(size_t)j*8 + r] = col[j]*sgn;
    out[(size_t)B*80 + (size_t)m*8 + r] = ws_fr[(size_t)m*8 + oi]; // friction_s
    out[(size_t)B*88 + (size_t)m*8 + r] = ws_st[(size_t)m*8 + oi]; // settle_s
    out[(size_t)B*96 + (size_t)m*8 + r] = (float)r;                // extraction_order
    if (r == 0) out[(size_t)B*104 + m] = resid;                    // residual
  }
}

extern "C" void kernel_launch(void* const* d_in, const int* in_sizes, int n_in,
                              void* d_out, int out_size, void* d_ws, size_t ws_size,
                              hipStream_t stream) {
  const float* A = (const float*)d_in[0];
  int B = in_sizes[0] / 64;
  float* out = (float*)d_out;

  double* ws_c     = (double*)d_ws;                 // B*9 f64
  double* ws_zi    = ws_c   + (size_t)B*9;          // B*8 f64
  double* ws_lam   = ws_zi  + (size_t)B*8;          // B*8 f64
  double* ws_scale = ws_lam + (size_t)B*8;          // B   f64
  float*  ws_fr    = (float*)(ws_scale + B);        // B*8 f32
  float*  ws_st    = ws_fr  + (size_t)B*8;          // B*8 f32

  int nt = B*8;
  hipLaunchKernelGGL(k1_charpoly, dim3((nt+255)/256), dim3(256), 0, stream,
                     A, ws_c, ws_zi, ws_scale, out + (size_t)B*72, B);
  hipLaunchKernelGGL(k2_roots, dim3((B+255)/256), dim3(256), 0, stream,
                     ws_c, ws_zi, ws_lam, ws_fr, ws_st, B);
  hipLaunchKernelGGL(k3_eig, dim3((nt+255)/256), dim3(256), 0, stream,
                     A, ws_c, ws_lam, ws_scale, ws_fr, ws_st, out, B);
}

// Round 2
// 178.887 us; speedup vs baseline: 3.2954x; 3.2954x over previous
//
#include <hip/hip_runtime.h>
#include <math.h>

#define DEV static __device__ __forceinline__

DEV double shfl8d(double v, int k){ return __shfl(v, k, 8); }
DEV double xor8d(double v, int msk){ return __shfl_xor(v, msk, 8); }
DEV float  shfl8f(float v, int k){ return __shfl(v, k, 8); }
DEV float  xor8f(float v, int msk){ return __shfl_xor(v, msk, 8); }
DEV int    xor8i(int v, int msk){ return __shfl_xor(v, msk, 8); }

DEV double sel8d(const double* a, int i){
  double v = a[0];
#pragma unroll
  for (int j=1;j<8;j++) v = (i==j) ? a[j] : v;
  return v;
}
DEV float sel8f(const float* a, int i){
  float v = a[0];
#pragma unroll
  for (int j=1;j<8;j++) v = (i==j) ? a[j] : v;
  return v;
}
DEV int sel8i(const int* a, int i){
  int v = a[0];
#pragma unroll
  for (int j=1;j<8;j++) v = (i==j) ? a[j] : v;
  return v;
}

#define CE(i,j) { double lo_ = fmin(d[i], d[j]); double hi_ = fmax(d[i], d[j]); d[i]=lo_; d[j]=hi_; }

// ---------------------------------------------------------------------------
// K1: scale, Ad, LeVerrier coefficients c[0..8], char_coeffs (f32), zi seeds.
// 8 threads per matrix; LDS-staged f64 8x8 matmuls (ds_read_b128).
// Arithmetic bitwise-identical to the R1 shuffle version (same FMA order).
// ---------------------------------------------------------------------------
__global__ __launch_bounds__(256) void k1_charpoly(
    const float* __restrict__ A, double* __restrict__ ws_c, double* __restrict__ ws_zi,
    double* __restrict__ ws_scale, float* __restrict__ out_char, int B)
{
#pragma clang fp contract(off)
  __shared__ double sM[32*66];   // 32 matrices/block, stride 66 dbl (bank-spread)
  int t = blockIdx.x*256 + threadIdx.x;
  int m = t >> 3, r = t & 7;
  bool act = (m < B);
  if (!act) m = 0;
  int ml = threadIdx.x >> 3;
  double* dm = sM + ml*66;

  const float* Am = A + (size_t)m*64 + (size_t)r*8;
  float a[8];
#pragma unroll
  for (int j=0;j<8;j++) a[j] = Am[j];
  float ss = a[0]*a[0];
#pragma unroll
  for (int j=1;j<8;j++) ss = ss + a[j]*a[j];
  ss = ss + xor8f(ss,1);
  ss = ss + xor8f(ss,2);
  ss = ss + xor8f(ss,4);
  float nrm = sqrtf(ss);
  double scale = (double)nrm / 2.8284271247461903;
  scale = fmax(scale, 1e-12);
  double Ad[8];
#pragma unroll
  for (int j=0;j<8;j++) Ad[j] = (double)a[j] / scale;

  double c[9];
#pragma unroll
  for (int j=0;j<9;j++) c[j] = 0.0;
  c[8] = 1.0;
  double Mc[8];
  // k=1: M1 = I; trace via same zero-preserving formula as R1
  {
    double s = Ad[0] * ((r==0)?1.0:0.0);
#pragma unroll
    for (int j=1;j<8;j++) s = s + Ad[j] * ((r==j)?1.0:0.0);
    s = s + xor8d(s,1);
    s = s + xor8d(s,2);
    s = s + xor8d(s,4);
    c[7] = -s / 1.0;
  }
  // k=2: M2 = Ad*I + c7*I  (bitwise == FMA chain over identity)
#pragma unroll
  for (int j=0;j<8;j++) Mc[j] = Ad[j] + ((j==r) ? c[7] : 0.0);
  {
    double s = Ad[0]*Mc[0];
#pragma unroll
    for (int j=1;j<8;j++) s = s + Ad[j]*Mc[j];
    s = s + xor8d(s,1);
    s = s + xor8d(s,2);
    s = s + xor8d(s,4);
    c[6] = -s / 2.0;
  }
  // k=3..8: staged matmul
#pragma unroll
  for (int k=3;k<=8;k++){
    double ck = c[9-k];
    double2* rowp = (double2*)(dm + r*8);
    rowp[0] = make_double2(Mc[0], Mc[1]);
    rowp[1] = make_double2(Mc[2], Mc[3]);
    rowp[2] = make_double2(Mc[4], Mc[5]);
    rowp[3] = make_double2(Mc[6], Mc[7]);
    __syncthreads();
    double Mn[8];
#pragma unroll
    for (int kk=0;kk<8;kk++){
      const double2* rp = (const double2*)(dm + kk*8);
      double2 q0 = rp[0], q1 = rp[1], q2 = rp[2], q3 = rp[3];
      if (kk == 0){
        Mn[0]=Ad[0]*q0.x; Mn[1]=Ad[0]*q0.y; Mn[2]=Ad[0]*q1.x; Mn[3]=Ad[0]*q1.y;
        Mn[4]=Ad[0]*q2.x; Mn[5]=Ad[0]*q2.y; Mn[6]=Ad[0]*q3.x; Mn[7]=Ad[0]*q3.y;
      } else {
        Mn[0]=fma(Ad[kk],q0.x,Mn[0]); Mn[1]=fma(Ad[kk],q0.y,Mn[1]);
        Mn[2]=fma(Ad[kk],q1.x,Mn[2]); Mn[3]=fma(Ad[kk],q1.y,Mn[3]);
        Mn[4]=fma(Ad[kk],q2.x,Mn[4]); Mn[5]=fma(Ad[kk],q2.y,Mn[5]);
        Mn[6]=fma(Ad[kk],q3.x,Mn[6]); Mn[7]=fma(Ad[kk],q3.y,Mn[7]);
      }
    }
    __syncthreads();
#pragma unroll
    for (int j=0;j<8;j++) Mc[j] = Mn[j] + ((j==r) ? ck : 0.0);
    double s = Ad[0]*Mc[0];
#pragma unroll
    for (int j=1;j<8;j++) s = s + Ad[j]*Mc[j];
    s = s + xor8d(s,1);
    s = s + xor8d(s,2);
    s = s + xor8d(s,4);
    c[8-k] = (-s) / (double)k;
  }

  if (act){
    double* cw = ws_c + (size_t)m*9;
    cw[r] = c[r];
    if (r == 0) cw[8] = c[8];
    out_char[(size_t)m*8 + r] = (float)c[r];
  }

  // zi = sort(diag(Ad)) + linspace(-1e-4, 1e-4, 8)
  double diag = sel8d(Ad, r);
  double d[8];
#pragma unroll
  for (int k=0;k<8;k++) d[k] = shfl8d(diag, k);
  CE(0,1) CE(2,3) CE(4,5) CE(6,7)
  CE(0,2) CE(1,3) CE(4,6) CE(5,7)
  CE(1,2) CE(5,6)
  CE(0,4) CE(1,5) CE(2,6) CE(3,7)
  CE(2,4) CE(3,5)
  CE(1,2) CE(3,4) CE(5,6)
  double step = 2e-4/7.0;
  double lin = (double)r * step + (-1e-4);
  if (r == 7) lin = 1e-4;
  if (act){
    ws_zi[(size_t)m*8 + r] = sel8d(d, r) + lin;
    if (r == 0) ws_scale[m] = scale;
  }
}

// ---------------------------------------------------------------------------
// K2: Laguerre rings + deflation + Newton polish. 1 thread per matrix.
// UNCHANGED from R1 (trajectory-critical: friction/settle bitwise).
// ---------------------------------------------------------------------------
__global__ __launch_bounds__(256) void k2_roots(
    const double* __restrict__ ws_c, const double* __restrict__ ws_zi,
    double* __restrict__ ws_lam, float* __restrict__ ws_fr, float* __restrict__ ws_st, int B)
{
#pragma clang fp contract(off)
  int m = blockIdx.x*256 + threadIdx.x;
  if (m >= B) return;
  const double* cp = ws_c + (size_t)m*9;
  double c[9], cl[9];
#pragma unroll
  for (int j=0;j<9;j++){ c[j] = cp[j]; cl[j] = c[j]; }
  const double* zp = ws_zi + (size_t)m*8;
  double roots[8];
  float* frp = ws_fr + (size_t)m*8;
  float* stp = ws_st + (size_t)m*8;
#pragma unroll
  for (int ri=0;ri<8;ri++){
    const int deg = 8 - ri;
    double z = zp[ri];
    float fr = 0.0f, st = 5.0f;
#pragma unroll
    for (int li=0; li<5; li++){
      double pv = cl[deg], dp = 0.0, d2 = 0.0;
#pragma unroll
      for (int j=deg-1;j>=0;j--){
        d2 = d2*z + dp;
        dp = dp*z + pv;
        pv = pv*z + cl[j];
      }
      float dp_abs = (float)fabs(dp);
      fr = fr + 1.0f/(dp_abs + 1e-8f);
      float pv_abs = (float)fabs(pv);
      if ((pv_abs < 1e-6f) && (st == 5.0f)) st = (float)li;
      bool ok = fabs(pv) > 1e-30;
      double ps = ok ? pv : 1.0;
      double G  = ok ? dp/ps : 0.0;
      double t2 = ok ? (2.0*d2)/ps : 0.0;
      double GG = G*G;
      double H  = GG - t2;
      double t3 = (double)deg*H - GG;
      double t4 = ((double)deg - 1.0) * t3;
      double disc = (t4 < 0.0) ? 0.0 : t4;
      double sq = sqrt(disc);
      double gp = G + sq, gm = G - sq;
      double den = (fabs(gp) >= fabs(gm)) ? gp : gm;
      bool dok = fabs(den) > 1e-20;
      double dsv = dok ? den : 1.0;
      z = z - (dok ? (double)deg/dsv : 0.0);
    }
    roots[ri] = z;
    frp[ri] = fr;
    stp[ri] = st;
    double b = cl[deg];
    double nc[8];
#pragma unroll
    for (int j=deg-1;j>=1;j--){
      double bn = cl[j] + z*b;
      nc[j] = b;
      b = bn;
    }
    nc[0] = b;
#pragma unroll
    for (int j=0;j<deg;j++) cl[j] = nc[j];
  }
#pragma unroll
  for (int it=0; it<3; it++){
#pragma unroll
    for (int i=0;i<8;i++){
      double rt = roots[i];
      double pv = 1.0, dp = 0.0;
#pragma unroll
      for (int j=7;j>=0;j--){
        dp = dp*rt + pv;
        pv = pv*rt + c[j];
      }
      bool ok = fabs(dp) > 1e-30;
      double dps = ok ? dp : 1.0;
      roots[i] = rt - (ok ? pv/dps : 0.0);
    }
  }
  double* lp = ws_lam + (size_t)m*8;
#pragma unroll
  for (int j=0;j<8;j++) lp[j] = roots[j];
}

// ---------------------------------------------------------------------------
// K3: resolvent eigenvectors (f32 front) + Newton-Schulz (f32, LDS) + outputs.
// 8 threads per matrix. M2..M8 in f32 registers; LDS-staged f32 matmuls.
// ---------------------------------------------------------------------------
__global__ __launch_bounds__(256) void k3_eig(
    const float* __restrict__ A, const double* __restrict__ ws_c,
    const double* __restrict__ ws_lam, const double* __restrict__ ws_scale,
    const float* __restrict__ ws_fr, const float* __restrict__ ws_st,
    float* __restrict__ out, int B)
{
  __shared__ float sV[32*72], sY[32*72], sT[32*72], sX[32*72];
  int t = blockIdx.x*256 + threadIdx.x;
  int m = t >> 3, r = t & 7;
  bool act = (m < B);
  if (!act) m = 0;
  int ml = threadIdx.x >> 3;
  float* mV = sV + ml*72;
  float* mY = sY + ml*72;
  float* mT = sT + ml*72;
  float* mX = sX + ml*72;
  float* mm = mV;                 // M-chain staging aliases the sV slice (phase-disjoint)

  const float* Am = A + (size_t)m*64 + (size_t)r*8;
  float a[8];
#pragma unroll
  for (int j=0;j<8;j++) a[j] = Am[j];
  float sc = (float)ws_scale[m];
  float Af[8];
#pragma unroll
  for (int j=0;j<8;j++) Af[j] = a[j] / sc;
  const double* cp = ws_c + (size_t)m*9;
  float cc[8];
#pragma unroll
  for (int j=1;j<8;j++) cc[j] = (float)cp[j];
  float lamf[8];
  const double* lp = ws_lam + (size_t)m*8;
#pragma unroll
  for (int j=0;j<8;j++) lamf[j] = (float)lp[j];

  // ---- M2..M8 in f32, LDS-staged matmuls ----
  float M[7][8];
  float Mc[8];
#pragma unroll
  for (int j=0;j<8;j++){ Mc[j] = Af[j] + ((j==r) ? cc[7] : 0.0f); M[0][j] = Mc[j]; }
#pragma unroll
  for (int k=3;k<=8;k++){
    float ck = cc[9-k];
    float4* rowp = (float4*)(mm + r*8);
    rowp[0] = make_float4(Mc[0],Mc[1],Mc[2],Mc[3]);
    rowp[1] = make_float4(Mc[4],Mc[5],Mc[6],Mc[7]);
    __syncthreads();
    float Mn[8];
#pragma unroll
    for (int kk=0;kk<8;kk++){
      const float4* rp = (const float4*)(mm + kk*8);
      float4 lo = rp[0], hi = rp[1];
      if (kk == 0){
        Mn[0]=Af[0]*lo.x; Mn[1]=Af[0]*lo.y; Mn[2]=Af[0]*lo.z; Mn[3]=Af[0]*lo.w;
        Mn[4]=Af[0]*hi.x; Mn[5]=Af[0]*hi.y; Mn[6]=Af[0]*hi.z; Mn[7]=Af[0]*hi.w;
      } else {
        Mn[0]=fmaf(Af[kk],lo.x,Mn[0]); Mn[1]=fmaf(Af[kk],lo.y,Mn[1]);
        Mn[2]=fmaf(Af[kk],lo.z,Mn[2]); Mn[3]=fmaf(Af[kk],lo.w,Mn[3]);
        Mn[4]=fmaf(Af[kk],hi.x,Mn[4]); Mn[5]=fmaf(Af[kk],hi.y,Mn[5]);
        Mn[6]=fmaf(Af[kk],hi.z,Mn[6]); Mn[7]=fmaf(Af[kk],hi.w,Mn[7]);
      }
    }
    __syncthreads();
#pragma unroll
    for (int j=0;j<8;j++){ Mc[j] = Mn[j] + ((j==r) ? ck : 0.0f); M[k-2][j] = Mc[j]; }
  }

  // ---- per eigenvalue: R(lam) Horner, row-norm butterfly argmax, vector ----
  float Vrow[8];
#pragma unroll
  for (int i=0;i<8;i++){
    float li = lamf[i];
    float R[8];
#pragma unroll
    for (int j=0;j<8;j++) R[j] = (j==r) ? 1.0f : 0.0f;
#pragma unroll
    for (int k=0;k<7;k++){
#pragma unroll
      for (int j=0;j<8;j++) R[j] = fmaf(R[j], li, M[k][j]);
    }
    // per-lane row norm^2 (R symmetric to ~1ulp => row norm == column norm)
    float nsq = R[0]*R[0];
#pragma unroll
    for (int j=1;j<8;j++) nsq = fmaf(R[j], R[j], nsq);
    int bi = r; float bv = nsq;
#pragma unroll
    for (int lvl=1; lvl<8; lvl<<=1){
      float ov = xor8f(bv, lvl);
      int   oi = xor8i(bi, lvl);
      bool take = (ov > bv) || ((ov == bv) && (oi < bi));
      bv = take ? ov : bv;
      bi = take ? oi : bi;
    }
    float vr = sel8f(R, bi);
    float nn = sqrtf(bv);
    Vrow[i] = vr / (nn + 1e-30f);
  }

  // ---- f32 Newton-Schulz phase through LDS ----
  __syncthreads();   // staging slice (mm==mV) is being reused as V
#pragma unroll
  for (int j=0;j<8;j++) mV[r*9+j] = Vrow[j];
  __syncthreads();
  float Yrow[8];
#pragma unroll
  for (int j=0;j<8;j++){
    float s = 0.0f;
#pragma unroll
    for (int k=0;k<8;k++) s = fmaf(mV[k*9+r], mV[k*9+j], s);
    Yrow[j] = s;
  }
  float Xrow[8];
#pragma unroll
  for (int j=0;j<8;j++) Xrow[j] = (j==r) ? 1.0f : 0.0f;
#pragma unroll
  for (int j=0;j<8;j++) mY[r*9+j] = Yrow[j];
  __syncthreads();
#pragma unroll
  for (int it=0; it<2; it++){
    float Trow[8];
#pragma unroll
    for (int j=0;j<8;j++) Trow[j] = ((j==r) ? 3.0f : 0.0f) - Yrow[j];
#pragma unroll
    for (int j=0;j<8;j++) mT[r*9+j] = Trow[j];
    __syncthreads();
    float Xn[8], Yn[8];
#pragma unroll
    for (int j=0;j<8;j++){
      float s = 0.0f;
#pragma unroll
      for (int k=0;k<8;k++) s = fmaf(Xrow[k], mT[k*9+j], s);
      Xn[j] = 0.5f*s;
    }
#pragma unroll
    for (int j=0;j<8;j++){
      float s = 0.0f;
#pragma unroll
      for (int k=0;k<8;k++) s = fmaf(Trow[k], mY[k*9+j], s);
      Yn[j] = 0.5f*s;
    }
    __syncthreads();
#pragma unroll
    for (int j=0;j<8;j++){ mY[r*9+j] = Yn[j]; Yrow[j] = Yn[j]; Xrow[j] = Xn[j]; }
    __syncthreads();
  }
#pragma unroll
  for (int j=0;j<8;j++) mX[r*9+j] = Xrow[j];
  __syncthreads();
  float Vn[8];
#pragma unroll
  for (int j=0;j<8;j++){
    float s = 0.0f;
#pragma unroll
    for (int k=0;k<8;k++) s = fmaf(Vrow[k], mX[k*9+j], s);
    Vn[j] = s;
  }
  __syncthreads();
#pragma unroll
  for (int j=0;j<8;j++) mV[r*9+j] = Vn[j];
  __syncthreads();
  float Erow[8];
#pragma unroll
  for (int j=0;j<8;j++){
    float s = 0.0f;
#pragma unroll
    for (int k=0;k<8;k++) s = fmaf(mV[k*9+r], mV[k*9+j], s);
    Erow[j] = s - ((j==r) ? 1.0f : 0.0f);
  }
  float rs = Erow[0]*Erow[0];
#pragma unroll
  for (int j=1;j<8;j++) rs = rs + Erow[j]*Erow[j];
  rs = rs + xor8f(rs,1);
  rs = rs + xor8f(rs,2);
  rs = rs + xor8f(rs,4);
  float resid = sqrtf(rs);
  float AVrow[8];
#pragma unroll
  for (int j=0;j<8;j++){
    float s = 0.0f;
#pragma unroll
    for (int k=0;k<8;k++) s = fmaf(a[k], mV[k*9+j], s);
    AVrow[j] = s;
  }
  float q[8];
#pragma unroll
  for (int i=0;i<8;i++) q[i] = Vn[i]*AVrow[i];
  float ev[8];
#pragma unroll
  for (int i=0;i<8;i++){
    float s = shfl8f(q[i], 0);
#pragma unroll
    for (int k=1;k<8;k++) s = s + shfl8f(q[i], k);
    ev[i] = s;
  }
  int perm[8];
  unsigned used = 0;
#pragma unroll
  for (int p=0;p<8;p++){
    int bi2 = -1; float bvv = 0.0f;
#pragma unroll
    for (int i2=0;i2<8;i2++){
      bool u = (used >> i2) & 1u;
      bool take = !u && (bi2 < 0 || ev[i2] < bvv);
      bi2 = take ? i2 : bi2;
      bvv = take ? ev[i2] : bvv;
    }
    perm[p] = bi2;
    used |= (1u << bi2);
  }
  int oi = sel8i(perm, r);
  float col[8];
#pragma unroll
  for (int j=0;j<8;j++) col[j] = mV[j*9 + oi];
  int mi = 0; float mv = fabsf(col[0]);
#pragma unroll
  for (int j=1;j<8;j++){
    float aj = fabsf(col[j]);
    if (aj > mv){ mv = aj; mi = j; }
  }
  float v0 = sel8f(col, mi);
  float sgn = (v0 > 0.0f) ? 1.0f : ((v0 < 0.0f) ? -1.0f : v0);
  if (act){
    out[(size_t)m*8 + r] = sel8f(ev, oi);                          // se
    float* svp = out + (size_t)B*8 + (size_t)m*64;                 // sv
#pragma unroll
    for (int j=0;j<8;j++) svp[(size_t)j*8 + r] = col[j]*sgn;
    out[(size_t)B*80 + (size_t)m*8 + r] = ws_fr[(size_t)m*8 + oi]; // friction_s
    out[(size_t)B*88 + (size_t)m*8 + r] = ws_st[(size_t)m*8 + oi]; // settle_s
    out[(size_t)B*96 + (size_t)m*8 + r] = (float)r;                // extraction_order
    if (r == 0) out[(size_t)B*104 + m] = resid;                    // residual
  }
}

extern "C" void kernel_launch(void* const* d_in, const int* in_sizes, int n_in,
                              void* d_out, int out_size, void* d_ws, size_t ws_size,
                              hipStream_t stream) {
  const float* A = (const float*)d_in[0];
  int B = in_sizes[0] / 64;
  float* out = (float*)d_out;

  double* ws_c     = (double*)d_ws;                 // B*9 f64
  double* ws_zi    = ws_c   + (size_t)B*9;          // B*8 f64
  double* ws_lam   = ws_zi  + (size_t)B*8;          // B*8 f64
  double* ws_scale = ws_lam + (size_t)B*8;          // B   f64
  float*  ws_fr    = (float*)(ws_scale + B);        // B*8 f32
  float*  ws_st    = ws_fr  + (size_t)B*8;          // B*8 f32

  int nt = B*8;
  hipLaunchKernelGGL(k1_charpoly, dim3((nt+255)/256), dim3(256), 0, stream,
                     A, ws_c, ws_zi, ws_scale, out + (size_t)B*72, B);
  hipLaunchKernelGGL(k2_roots, dim3((B+255)/256), dim3(256), 0, stream,
                     ws_c, ws_zi, ws_lam, ws_fr, ws_st, B);
  hipLaunchKernelGGL(k3_eig, dim3((nt+255)/256), dim3(256), 0, stream,
                     A, ws_c, ws_lam, ws_scale, ws_fr, ws_st, out, B);
}